// Round 4
// baseline (363.360 us; speedup 1.0000x reference)
//
#include <hip/hip_runtime.h>
#include <hip/hip_cooperative_groups.h>

namespace cg = cooperative_groups;

static constexpr int D = 2048;
static constexpr int H = 4096;
static constexpr int KSTEP = 4;
static constexpr int MAX_STEPS = 64;
static constexpr float MOMC = 0.9f;

static constexpr int GRID = 256;
static constexpr int BLOCK = 1024;
static constexpr int NTH = GRID * BLOCK;   // 262144
static constexpr int NW = NTH / 64;        // 4096 waves

struct Params {
  const float* query;
  const float* hg_Wih; const float* hg_Whh; const float* hg_bih; const float* hg_bhh;
  const float* hd_W; const float* hd_b;
  const float* hc_W; const float* hc_b;
  const float* lg_Wih; const float* lg_Whh; const float* lg_bih; const float* lg_bhh;
  const float* lo_W; const float* lo_b;
  const float* halt_W; const float* halt_b;
  const float* reset_W; const float* reset_b;
  const float* li_W; const float* li_b;
  float* ws; float* out;
};

__device__ __forceinline__ float sigmoidf_(float x) { return 1.f / (1.f + expf(-x)); }

__device__ __forceinline__ float wred(float v) {
  #pragma unroll
  for (int off = 1; off < 64; off <<= 1) v += __shfl_xor(v, off, 64);
  return v;
}

// One D-length (2048) row held in registers: 8 x float4 = 32 VGPRs.
struct RowD { float4 r[8]; };

__device__ __forceinline__ void loadrow(RowD& d, const float* __restrict__ row, int lane) {
  #pragma unroll
  for (int g = 0; g < 8; ++g)
    d.r[g] = *reinterpret_cast<const float4*>(row + g * 256 + lane * 4);
}

__device__ __forceinline__ float dotrow(const RowD& a, const float* __restrict__ v, int lane) {
  float s0 = 0.f, s1 = 0.f, s2 = 0.f, s3 = 0.f;
  #pragma unroll
  for (int g = 0; g < 8; g += 4) {
    float4 b0 = *reinterpret_cast<const float4*>(v + (g + 0) * 256 + lane * 4);
    float4 b1 = *reinterpret_cast<const float4*>(v + (g + 1) * 256 + lane * 4);
    float4 b2 = *reinterpret_cast<const float4*>(v + (g + 2) * 256 + lane * 4);
    float4 b3 = *reinterpret_cast<const float4*>(v + (g + 3) * 256 + lane * 4);
    s0 = fmaf(a.r[g + 0].x, b0.x, s0); s0 = fmaf(a.r[g + 0].y, b0.y, s0);
    s0 = fmaf(a.r[g + 0].z, b0.z, s0); s0 = fmaf(a.r[g + 0].w, b0.w, s0);
    s1 = fmaf(a.r[g + 1].x, b1.x, s1); s1 = fmaf(a.r[g + 1].y, b1.y, s1);
    s1 = fmaf(a.r[g + 1].z, b1.z, s1); s1 = fmaf(a.r[g + 1].w, b1.w, s1);
    s2 = fmaf(a.r[g + 2].x, b2.x, s2); s2 = fmaf(a.r[g + 2].y, b2.y, s2);
    s2 = fmaf(a.r[g + 2].z, b2.z, s2); s2 = fmaf(a.r[g + 2].w, b2.w, s2);
    s3 = fmaf(a.r[g + 3].x, b3.x, s3); s3 = fmaf(a.r[g + 3].y, b3.y, s3);
    s3 = fmaf(a.r[g + 3].z, b3.z, s3); s3 = fmaf(a.r[g + 3].w, b3.w, s3);
  }
  return (s0 + s1) + (s2 + s3);
}

// Plain streaming dot for the few misc H-dots / rare paths.
template<int LEN>
__device__ __forceinline__ float dotw(const float* __restrict__ row,
                                      const float* __restrict__ vec, int lane) {
  float s0 = 0.f, s1 = 0.f, s2 = 0.f, s3 = 0.f;
  #pragma unroll
  for (int k = 0; k < LEN; k += 1024) {
    int i = k + lane * 4;
    float4 a0 = *reinterpret_cast<const float4*>(row + i);
    float4 a1 = *reinterpret_cast<const float4*>(row + i + 256);
    float4 a2 = *reinterpret_cast<const float4*>(row + i + 512);
    float4 a3 = *reinterpret_cast<const float4*>(row + i + 768);
    float4 b0 = *reinterpret_cast<const float4*>(vec + i);
    float4 b1 = *reinterpret_cast<const float4*>(vec + i + 256);
    float4 b2 = *reinterpret_cast<const float4*>(vec + i + 512);
    float4 b3 = *reinterpret_cast<const float4*>(vec + i + 768);
    s0 = fmaf(a0.x, b0.x, s0); s0 = fmaf(a0.y, b0.y, s0);
    s0 = fmaf(a0.z, b0.z, s0); s0 = fmaf(a0.w, b0.w, s0);
    s1 = fmaf(a1.x, b1.x, s1); s1 = fmaf(a1.y, b1.y, s1);
    s1 = fmaf(a1.z, b1.z, s1); s1 = fmaf(a1.w, b1.w, s1);
    s2 = fmaf(a2.x, b2.x, s2); s2 = fmaf(a2.y, b2.y, s2);
    s2 = fmaf(a2.z, b2.z, s2); s2 = fmaf(a2.w, b2.w, s2);
    s3 = fmaf(a3.x, b3.x, s3); s3 = fmaf(a3.y, b3.y, s3);
    s3 = fmaf(a3.z, b3.z, s3); s3 = fmaf(a3.w, b3.w, s3);
  }
  return (s0 + s1) + (s2 + s3);
}

__device__ __forceinline__ const float* brow(const Params& p, int gw) {
  return gw < D ? p.lo_W + (size_t)gw * D : (gw == D ? p.halt_W + H : p.reset_W + H);
}

// ---- A-phase variants (all weight loads burst-issued into registers) ----

// step 0: gi q-part, 3H rows, exactly 3 per wave (12288 = 3*NW)
__device__ __forceinline__ void A_step0(const Params& p, const float* sh_q,
                                        float* qc, int gw, int lane) {
  const int t0 = gw, t1 = gw + NW, t2 = gw + 2 * NW;
  RowD r0, r1;
  loadrow(r0, p.hg_Wih + (size_t)t0 * (2 * D), lane);
  loadrow(r1, p.hg_Wih + (size_t)t1 * (2 * D), lane);
  float s = wred(dotrow(r0, sh_q, lane));
  if (lane == 0) qc[t0] = s;
  loadrow(r0, p.hg_Wih + (size_t)t2 * (2 * D), lane);
  s = wred(dotrow(r1, sh_q, lane));
  if (lane == 0) qc[t1] = s;
  s = wred(dotrow(r0, sh_q, lane));
  if (lane == 0) qc[t2] = s;
}

// non-update steps: ghl = lg_Whh @ l + bhh (6144 rows, <=2 per wave)
__device__ __forceinline__ void A_ghl(const Params& p, const float* sh_l,
                                      float* ghl, int gw, int lane) {
  const int t0 = gw, t1 = gw + NW;
  const bool h1 = t1 < 3 * D;
  RowD r0, r1;
  loadrow(r0, p.lg_Whh + (size_t)t0 * D, lane);
  if (h1) loadrow(r1, p.lg_Whh + (size_t)t1 * D, lane);
  float s = wred(dotrow(r0, sh_l, lane)) + p.lg_bhh[t0];
  if (lane == 0) ghl[t0] = s;
  if (h1) {
    s = wred(dotrow(r1, sh_l, lane)) + p.lg_bhh[t1];
    if (lane == 0) ghl[t1] = s;
  }
}

// update steps >= 4: gi l-part (3H rows of D), Whh as 6H half-rows of 2048,
// ghl (3D rows). 43008 tasks, 2-deep software pipeline.
__device__ __forceinline__ void big_task(const Params& p, int t,
    const float* sh_l, const float* sh_h, float* gi_l, float* ghh, float* ghl,
    const float** row, const float** vec, float** dst, float* bias) {
  if (t < 3 * H) {
    *row = p.hg_Wih + (size_t)t * (2 * D) + D; *vec = sh_l; *dst = gi_l + t; *bias = 0.f;
  } else if (t < 9 * H) {
    int m = t - 3 * H; int rr = m >> 1, hf = m & 1;
    *row = p.hg_Whh + (size_t)rr * H + hf * 2048; *vec = sh_h + hf * 2048;
    *dst = ghh + hf * 3 * H + rr; *bias = 0.f;
  } else {
    int j = t - 9 * H;
    *row = p.lg_Whh + (size_t)j * D; *vec = sh_l; *dst = ghl + j; *bias = p.lg_bhh[j];
  }
}

__device__ void A_big(const Params& p, const float* sh_l, const float* sh_h,
                      float* gi_l, float* ghh, float* ghl, int gw, int lane) {
  const int total = 9 * H + 3 * D;  // 43008
  const float *row0, *vec0; float *dst0; float b0;
  big_task(p, gw, sh_l, sh_h, gi_l, ghh, ghl, &row0, &vec0, &dst0, &b0);
  RowD r0, r1;
  loadrow(r0, row0, lane);
  int tn = gw + NW;
  while (true) {
    const float *row1, *vec1; float *dst1; float b1;
    bool h1 = tn < total;
    if (h1) {
      big_task(p, tn, sh_l, sh_h, gi_l, ghh, ghl, &row1, &vec1, &dst1, &b1);
      loadrow(r1, row1, lane);
    }
    float s = wred(dotrow(r0, vec0, lane)) + b0;
    if (lane == 0) *dst0 = s;
    if (!h1) break;
    vec0 = vec1; dst0 = dst1; b0 = b1; r0 = r1;
    tn += NW;
  }
}

__global__ void __launch_bounds__(BLOCK, 4) reasoning_kernel(Params p) {
  cg::grid_group grid = cg::this_grid();
  const int tid = blockIdx.x * blockDim.x + threadIdx.x;
  const int lane = threadIdx.x & 63;
  const int gw = tid >> 6;

  __shared__ __align__(16) float sh_h[H];
  __shared__ __align__(16) float sh_l[D];
  __shared__ __align__(16) float sh_q[D];
  __shared__ __align__(16) float sh_dir[D];

  // ws layout (floats)
  float* qc    = p.ws;               // 3H  q-part of gi (step-invariant)
  float* gi_l  = qc + 3 * H;         // 3H  l-part of gi (upd steps >= 4)
  float* ghh   = gi_l + 3 * H;       // 6H  Whh half-dots
  float* ghl2  = ghh + 6 * H;        // 2 x 3D  (parity ping-pong)
  float* gil   = ghl2 + 6 * D;       // 3D  lg_Wih @ dirv + bih (cached)
  float* dhalf = gil + 3 * D;        // 2D  hd_W half-dots
  float* resv2 = dhalf + 2 * D;      // 2 x D  (parity ping-pong)
  float* lrs   = resv2 + 2 * D;      // D   reset projection
  float* scal  = lrs + D;            // 16: [0]=rawconv [1]=halt_h [2]=reset_h
                                     //     [8+par*2+{0,1}] = halt_l, reset_l

  for (int j = threadIdx.x; j < H; j += blockDim.x) sh_h[j] = 0.f;
  for (int j = threadIdx.x; j < D; j += blockDim.x) { sh_l[j] = 0.f; sh_q[j] = p.query[j]; }
  __syncthreads();

  float cum = 0.f, rw = 0.f, mom = 0.f, rawconv = 0.f, sum_reg = 0.f;
  bool finished = false;
  int last_step = -1;

  for (int step = 0; step < MAX_STEPS; ++step) {
    const int par = step & 1;
    const bool upd = (step & 3) == 0;
    float* ghl  = ghl2 + par * 3 * D;
    float* resv = resv2 + par * D;

    // ---------------- A phase (pre-barrier burst) ----------------
    if (upd) {
      if (step == 0) A_step0(p, sh_q, qc, gw, lane);
      else           A_big(p, sh_l, sh_h, gi_l, ghh, ghl, gw, lane);
    } else {
      A_ghl(p, sh_l, ghl, gw, lane);
    }

    // B-phase prefetch (non-upd: held across S1; upd prefetches before S3)
    RowD rB;
    const bool haveB = gw < D + 2;
    if (!upd && haveB) loadrow(rB, brow(p, gw), lane);

    grid.sync();  // S1

    // ---------------- deferred scalar resolution for step-1 ----------------
    if (step > 0) {
      const int pq = par ^ 1;
      if (((step - 1) & 3) == 0) rawconv = scal[0];
      mom = MOMC * mom + (1.f - MOMC) * rawconv;
      float halt = sigmoidf_(scal[1] + scal[8 + pq * 2 + 0] + p.halt_b[0]);
      float pp = fminf(halt, 1.f - cum);
      cum += pp; rw += pp;
      if (tid < D) sum_reg += pp * resv2[pq * D + tid];
      if (cum > 0.95f) { finished = true; break; }
      float reset_p = sigmoidf_(scal[2] + scal[8 + pq * 2 + 1] +
                                p.reset_W[H + D] * mom + p.reset_b[0]);
      if ((reset_p > 0.7f) && ((step - 1) > KSTEP)) {
        // rare: l was reset after step-1; recompute l and redo A with it
        for (int t = gw; t < D; t += NW) {
          float s = wred(dotw<H>(p.li_W + (size_t)t * H, sh_h, lane)) + p.li_b[t];
          if (lane == 0) lrs[t] = tanhf(s);
        }
        grid.sync();
        for (int j = threadIdx.x; j < D; j += blockDim.x) sh_l[j] = lrs[j];
        __syncthreads();
        if (upd) A_big(p, sh_l, sh_h, gi_l, ghh, ghl, gw, lane);
        else     A_ghl(p, sh_l, ghl, gw, lane);
        grid.sync();
      }
    }

    // ---------------- update-step mid phases ----------------
    if (upd) {
      // P2: h-combine (block-local, identical across blocks)
      if (step == 0) {
        for (int i = threadIdx.x; i < H; i += blockDim.x) {
          float r = sigmoidf_(qc[i] + p.hg_bih[i] + p.hg_bhh[i]);
          float z = sigmoidf_(qc[H + i] + p.hg_bih[H + i] + p.hg_bhh[H + i]);
          float n = tanhf(qc[2 * H + i] + p.hg_bih[2 * H + i] + r * p.hg_bhh[2 * H + i]);
          sh_h[i] = (1.f - z) * n;  // + z*0
        }
      } else {
        for (int i = threadIdx.x; i < H; i += blockDim.x) {
          float g0 = qc[i] + gi_l[i] + p.hg_bih[i];
          float g1 = qc[H + i] + gi_l[H + i] + p.hg_bih[H + i];
          float g2 = qc[2 * H + i] + gi_l[2 * H + i] + p.hg_bih[2 * H + i];
          float h0 = ghh[i] + ghh[3 * H + i] + p.hg_bhh[i];
          float h1 = ghh[H + i] + ghh[4 * H + i] + p.hg_bhh[H + i];
          float h2 = ghh[2 * H + i] + ghh[5 * H + i] + p.hg_bhh[2 * H + i];
          float r = sigmoidf_(g0 + h0);
          float z = sigmoidf_(g1 + h1);
          float n = tanhf(g2 + r * h2);
          sh_h[i] = (1.f - z) * n + z * sh_h[i];
        }
      }
      __syncthreads();

      // P3: hd_W as 4096 half-row tasks + 3 misc H-dots
      if (gw < 2 * D) {
        int row = gw >> 1, half = gw & 1;
        RowD r3;
        loadrow(r3, p.hd_W + (size_t)row * H + half * 2048, lane);
        float s = wred(dotrow(r3, sh_h + half * 2048, lane));
        if (lane == 0) dhalf[half * D + row] = s;
      } else if (gw == 2 * D) {
        float s = wred(dotw<H>(p.hc_W, sh_h, lane)) + p.hc_b[0];
        if (lane == 0) scal[0] = sigmoidf_(s);
      } else if (gw == 2 * D + 1) {
        float s = wred(dotw<H>(p.halt_W, sh_h, lane));
        if (lane == 0) scal[1] = s;
      } else if (gw == 2 * D + 2) {
        float s = wred(dotw<H>(p.reset_W, sh_h, lane));
        if (lane == 0) scal[2] = s;
      }

      // P4 prefetch (held across S2)
      RowD r40, r41;
      const bool h41 = (gw + NW) < 3 * D;
      loadrow(r40, p.lg_Wih + (size_t)gw * D, lane);
      if (h41) loadrow(r41, p.lg_Wih + (size_t)(gw + NW) * D, lane);
      grid.sync();  // S2

      // directive combine (block-local)
      for (int j = threadIdx.x; j < D; j += blockDim.x)
        sh_dir[j] = tanhf(dhalf[j] + dhalf[D + j] + p.hd_b[j]);
      __syncthreads();

      // P4 compute: gil = lg_Wih @ dirv + bih
      {
        float s = wred(dotrow(r40, sh_dir, lane)) + p.lg_bih[gw];
        if (lane == 0) gil[gw] = s;
      }
      if (h41) {
        float s = wred(dotrow(r41, sh_dir, lane)) + p.lg_bih[gw + NW];
        if (lane == 0) gil[gw + NW] = s;
      }

      if (haveB) loadrow(rB, brow(p, gw), lane);
      grid.sync();  // S3
    }

    // ---------------- P5: l-combine (block-local) ----------------
    if (step == 0) {
      for (int j = threadIdx.x; j < D; j += blockDim.x) {
        float r = sigmoidf_(gil[j] + p.lg_bhh[j]);
        float z = sigmoidf_(gil[D + j] + p.lg_bhh[D + j]);
        float n = tanhf(gil[2 * D + j] + r * p.lg_bhh[2 * D + j]);
        sh_l[j] = (1.f - z) * n;  // + z*0
      }
    } else {
      for (int j = threadIdx.x; j < D; j += blockDim.x) {
        float r = sigmoidf_(gil[j] + ghl[j]);
        float z = sigmoidf_(gil[D + j] + ghl[D + j]);
        float n = tanhf(gil[2 * D + j] + r * ghl[2 * D + j]);
        sh_l[j] = (1.f - z) * n + z * sh_l[j];
      }
    }
    __syncthreads();

    // ---------------- B compute: res / halt_l / reset_l ----------------
    if (haveB) {
      float s = wred(dotrow(rB, sh_l, lane));
      if (gw < D)      { if (lane == 0) resv[gw] = tanhf(s + p.lo_b[gw]); }
      else if (gw == D){ if (lane == 0) scal[8 + par * 2 + 0] = s; }
      else             { if (lane == 0) scal[8 + par * 2 + 1] = s; }
    }
    last_step = step;
    // no trailing sync: next iteration's S1 orders resv/scal for resolution
  }

  if (!finished && last_step >= 0) {
    grid.sync();
    const int pq = last_step & 1;
    float halt = sigmoidf_(scal[1] + scal[8 + pq * 2 + 0] + p.halt_b[0]);
    float pp = fminf(halt, 1.f - cum);
    rw += pp;
    if (tid < D) sum_reg += pp * resv2[pq * D + tid];
  }

  if (tid < D) p.out[tid] = sum_reg / fmaxf(rw, 1e-8f);
}

extern "C" void kernel_launch(void* const* d_in, const int* in_sizes, int n_in,
                              void* d_out, int out_size, void* d_ws, size_t ws_size,
                              hipStream_t stream) {
  Params prm;
  prm.query   = (const float*)d_in[0];
  prm.hg_Wih  = (const float*)d_in[1];
  prm.hg_Whh  = (const float*)d_in[2];
  prm.hg_bih  = (const float*)d_in[3];
  prm.hg_bhh  = (const float*)d_in[4];
  prm.hd_W    = (const float*)d_in[5];
  prm.hd_b    = (const float*)d_in[6];
  prm.hc_W    = (const float*)d_in[7];
  prm.hc_b    = (const float*)d_in[8];
  prm.lg_Wih  = (const float*)d_in[9];
  prm.lg_Whh  = (const float*)d_in[10];
  prm.lg_bih  = (const float*)d_in[11];
  prm.lg_bhh  = (const float*)d_in[12];
  prm.lo_W    = (const float*)d_in[13];
  prm.lo_b    = (const float*)d_in[14];
  prm.halt_W  = (const float*)d_in[15];
  prm.halt_b  = (const float*)d_in[16];
  prm.reset_W = (const float*)d_in[17];
  prm.reset_b = (const float*)d_in[18];
  prm.li_W    = (const float*)d_in[19];
  prm.li_b    = (const float*)d_in[20];
  prm.ws  = (float*)d_ws;
  prm.out = (float*)d_out;

  void* args[] = { &prm };
  const int grids[3] = { GRID, GRID / 2, GRID / 4 };
  for (int g = 0; g < 3; ++g) {
    hipError_t e = hipLaunchCooperativeKernel((const void*)reasoning_kernel,
                                              dim3(grids[g]), dim3(BLOCK),
                                              args, 0, stream);
    if (e == hipSuccess) break;
  }
}

// Round 5
// 278.014 us; speedup vs baseline: 1.3070x; 1.3070x over previous
//
#include <hip/hip_runtime.h>
#include <hip/hip_cooperative_groups.h>

namespace cg = cooperative_groups;

static constexpr int D = 2048;
static constexpr int H = 4096;
static constexpr int KSTEP = 4;
static constexpr int MAX_STEPS = 64;
static constexpr float MOMC = 0.9f;

static constexpr int GRID = 256;
static constexpr int BLOCK = 512;

struct Params {
  const float* query;
  const float* hg_Wih; const float* hg_Whh; const float* hg_bih; const float* hg_bhh;
  const float* hd_W; const float* hd_b;
  const float* hc_W; const float* hc_b;
  const float* lg_Wih; const float* lg_Whh; const float* lg_bih; const float* lg_bhh;
  const float* lo_W; const float* lo_b;
  const float* halt_W; const float* halt_b;
  const float* reset_W; const float* reset_b;
  const float* li_W; const float* li_b;
  float* ws; float* out;
};

__device__ __forceinline__ float sigmoidf_(float x) { return 1.f / (1.f + expf(-x)); }

__device__ __forceinline__ float wred(float v) {
  #pragma unroll
  for (int off = 1; off < 64; off <<= 1) v += __shfl_xor(v, off, 64);
  return v;
}

// ---- deep-ILP dots: ALL weight loads issued before any FMA needs them ----
// Reduction order identical to R2's dotw (s0..s3 over strided segments).

// single 2048-length row (8 float4 in flight)
__device__ __forceinline__ float dot8(const float* __restrict__ row,
                                      const float* __restrict__ vec, int lane) {
  float4 a[8];
  #pragma unroll
  for (int g = 0; g < 8; ++g)
    a[g] = *reinterpret_cast<const float4*>(row + g * 256 + lane * 4);
  float s0 = 0.f, s1 = 0.f, s2 = 0.f, s3 = 0.f;
  #pragma unroll
  for (int g = 0; g < 8; g += 4) {
    float4 b0 = *reinterpret_cast<const float4*>(vec + (g + 0) * 256 + lane * 4);
    float4 b1 = *reinterpret_cast<const float4*>(vec + (g + 1) * 256 + lane * 4);
    float4 b2 = *reinterpret_cast<const float4*>(vec + (g + 2) * 256 + lane * 4);
    float4 b3 = *reinterpret_cast<const float4*>(vec + (g + 3) * 256 + lane * 4);
    s0 = fmaf(a[g+0].x, b0.x, s0); s0 = fmaf(a[g+0].y, b0.y, s0);
    s0 = fmaf(a[g+0].z, b0.z, s0); s0 = fmaf(a[g+0].w, b0.w, s0);
    s1 = fmaf(a[g+1].x, b1.x, s1); s1 = fmaf(a[g+1].y, b1.y, s1);
    s1 = fmaf(a[g+1].z, b1.z, s1); s1 = fmaf(a[g+1].w, b1.w, s1);
    s2 = fmaf(a[g+2].x, b2.x, s2); s2 = fmaf(a[g+2].y, b2.y, s2);
    s2 = fmaf(a[g+2].z, b2.z, s2); s2 = fmaf(a[g+2].w, b2.w, s2);
    s3 = fmaf(a[g+3].x, b3.x, s3); s3 = fmaf(a[g+3].y, b3.y, s3);
    s3 = fmaf(a[g+3].z, b3.z, s3); s3 = fmaf(a[g+3].w, b3.w, s3);
  }
  return (s0 + s1) + (s2 + s3);
}

// two independent 2048-length rows (16 float4 in flight)
__device__ __forceinline__ void dot8x2(const float* __restrict__ r0,
                                       const float* __restrict__ r1,
                                       const float* __restrict__ vec,
                                       int lane, float& o0, float& o1) {
  float4 a[8], c[8];
  #pragma unroll
  for (int g = 0; g < 8; ++g)
    a[g] = *reinterpret_cast<const float4*>(r0 + g * 256 + lane * 4);
  #pragma unroll
  for (int g = 0; g < 8; ++g)
    c[g] = *reinterpret_cast<const float4*>(r1 + g * 256 + lane * 4);
  float s0 = 0.f, s1 = 0.f, s2 = 0.f, s3 = 0.f;
  float t0 = 0.f, t1 = 0.f, t2 = 0.f, t3 = 0.f;
  #pragma unroll
  for (int g = 0; g < 8; g += 4) {
    float4 b0 = *reinterpret_cast<const float4*>(vec + (g + 0) * 256 + lane * 4);
    float4 b1 = *reinterpret_cast<const float4*>(vec + (g + 1) * 256 + lane * 4);
    float4 b2 = *reinterpret_cast<const float4*>(vec + (g + 2) * 256 + lane * 4);
    float4 b3 = *reinterpret_cast<const float4*>(vec + (g + 3) * 256 + lane * 4);
    s0 = fmaf(a[g+0].x, b0.x, s0); s0 = fmaf(a[g+0].y, b0.y, s0);
    s0 = fmaf(a[g+0].z, b0.z, s0); s0 = fmaf(a[g+0].w, b0.w, s0);
    s1 = fmaf(a[g+1].x, b1.x, s1); s1 = fmaf(a[g+1].y, b1.y, s1);
    s1 = fmaf(a[g+1].z, b1.z, s1); s1 = fmaf(a[g+1].w, b1.w, s1);
    s2 = fmaf(a[g+2].x, b2.x, s2); s2 = fmaf(a[g+2].y, b2.y, s2);
    s2 = fmaf(a[g+2].z, b2.z, s2); s2 = fmaf(a[g+2].w, b2.w, s2);
    s3 = fmaf(a[g+3].x, b3.x, s3); s3 = fmaf(a[g+3].y, b3.y, s3);
    s3 = fmaf(a[g+3].z, b3.z, s3); s3 = fmaf(a[g+3].w, b3.w, s3);
    t0 = fmaf(c[g+0].x, b0.x, t0); t0 = fmaf(c[g+0].y, b0.y, t0);
    t0 = fmaf(c[g+0].z, b0.z, t0); t0 = fmaf(c[g+0].w, b0.w, t0);
    t1 = fmaf(c[g+1].x, b1.x, t1); t1 = fmaf(c[g+1].y, b1.y, t1);
    t1 = fmaf(c[g+1].z, b1.z, t1); t1 = fmaf(c[g+1].w, b1.w, t1);
    t2 = fmaf(c[g+2].x, b2.x, t2); t2 = fmaf(c[g+2].y, b2.y, t2);
    t2 = fmaf(c[g+2].z, b2.z, t2); t2 = fmaf(c[g+2].w, b2.w, t2);
    t3 = fmaf(c[g+3].x, b3.x, t3); t3 = fmaf(c[g+3].y, b3.y, t3);
    t3 = fmaf(c[g+3].z, b3.z, t3); t3 = fmaf(c[g+3].w, b3.w, t3);
  }
  o0 = (s0 + s1) + (s2 + s3);
  o1 = (t0 + t1) + (t2 + t3);
}

// single 4096-length row (16 float4 in flight)
__device__ __forceinline__ float dot16(const float* __restrict__ row,
                                       const float* __restrict__ vec, int lane) {
  float4 a[16];
  #pragma unroll
  for (int g = 0; g < 16; ++g)
    a[g] = *reinterpret_cast<const float4*>(row + g * 256 + lane * 4);
  float s0 = 0.f, s1 = 0.f, s2 = 0.f, s3 = 0.f;
  #pragma unroll
  for (int g = 0; g < 16; g += 4) {
    float4 b0 = *reinterpret_cast<const float4*>(vec + (g + 0) * 256 + lane * 4);
    float4 b1 = *reinterpret_cast<const float4*>(vec + (g + 1) * 256 + lane * 4);
    float4 b2 = *reinterpret_cast<const float4*>(vec + (g + 2) * 256 + lane * 4);
    float4 b3 = *reinterpret_cast<const float4*>(vec + (g + 3) * 256 + lane * 4);
    s0 = fmaf(a[g+0].x, b0.x, s0); s0 = fmaf(a[g+0].y, b0.y, s0);
    s0 = fmaf(a[g+0].z, b0.z, s0); s0 = fmaf(a[g+0].w, b0.w, s0);
    s1 = fmaf(a[g+1].x, b1.x, s1); s1 = fmaf(a[g+1].y, b1.y, s1);
    s1 = fmaf(a[g+1].z, b1.z, s1); s1 = fmaf(a[g+1].w, b1.w, s1);
    s2 = fmaf(a[g+2].x, b2.x, s2); s2 = fmaf(a[g+2].y, b2.y, s2);
    s2 = fmaf(a[g+2].z, b2.z, s2); s2 = fmaf(a[g+2].w, b2.w, s2);
    s3 = fmaf(a[g+3].x, b3.x, s3); s3 = fmaf(a[g+3].y, b3.y, s3);
    s3 = fmaf(a[g+3].z, b3.z, s3); s3 = fmaf(a[g+3].w, b3.w, s3);
  }
  return (s0 + s1) + (s2 + s3);
}

__global__ void __launch_bounds__(BLOCK, 2) reasoning_kernel(Params p) {
  cg::grid_group grid = cg::this_grid();
  const int tid = blockIdx.x * blockDim.x + threadIdx.x;
  const int nth = gridDim.x * blockDim.x;
  const int lane = threadIdx.x & 63;
  const int gw = tid >> 6;
  const int nw = nth >> 6;

  __shared__ __align__(16) float sh_h[H];
  __shared__ __align__(16) float sh_l[D];
  __shared__ __align__(16) float sh_q[D];
  __shared__ __align__(16) float sh_dir[D];

  // ws layout (floats)
  float* qc    = p.ws;           // 3H  q-part of gi (step-invariant)
  float* gi_l  = qc + 3 * H;     // 3H  l-part of gi (upd steps >= 4)
  float* ghh   = gi_l + 3 * H;   // 3H  hg_Whh @ h + bhh
  float* ghl2  = ghh + 3 * H;    // 2 x 3D parity ping-pong
  float* gil   = ghl2 + 6 * D;   // 3D  lg_Wih @ dirv + bih (cached)
  float* dirv  = gil + 3 * D;    // D
  float* resv2 = dirv + D;       // 2 x D parity ping-pong
  float* lrs   = resv2 + 2 * D;  // D  reset projection
  float* scal  = lrs + D;        // 16: [0]=rawconv [1]=halt_h [2]=reset_h
                                 //     [8+par*2+{0,1}] = halt_l, reset_l

  for (int j = threadIdx.x; j < H; j += blockDim.x) sh_h[j] = 0.f;
  for (int j = threadIdx.x; j < D; j += blockDim.x) { sh_l[j] = 0.f; sh_q[j] = p.query[j]; }
  __syncthreads();

  float cum = 0.f, rw = 0.f, mom = 0.f, sum_reg = 0.f;

  for (int step = 0; step < MAX_STEPS; ++step) {
    const int par = step & 1;
    const bool upd = (step & 3) == 0;
    float* ghl  = ghl2 + par * 3 * D;
    float* resv = resv2 + par * D;

    // ---------------- A phase ----------------
    if (upd) {
      if (step == 0) {
        for (int t = gw * 2; t < 3 * H; t += nw * 2) {
          float o0, o1;
          dot8x2(p.hg_Wih + (size_t)t * (2 * D),
                 p.hg_Wih + (size_t)(t + 1) * (2 * D), sh_q, lane, o0, o1);
          o0 = wred(o0); o1 = wred(o1);
          if (lane == 0) { qc[t] = o0; qc[t + 1] = o1; }
        }
      } else {
        for (int t = gw * 2; t < 3 * H; t += nw * 2) {      // gi l-part
          float o0, o1;
          dot8x2(p.hg_Wih + (size_t)t * (2 * D) + D,
                 p.hg_Wih + (size_t)(t + 1) * (2 * D) + D, sh_l, lane, o0, o1);
          o0 = wred(o0); o1 = wred(o1);
          if (lane == 0) { gi_l[t] = o0; gi_l[t + 1] = o1; }
        }
        for (int t = gw; t < 3 * H; t += nw) {              // Whh @ h
          float s = wred(dot16(p.hg_Whh + (size_t)t * H, sh_h, lane)) + p.hg_bhh[t];
          if (lane == 0) ghh[t] = s;
        }
        for (int t = gw * 2; t < 3 * D; t += nw * 2) {      // lg_Whh @ l
          float o0, o1;
          dot8x2(p.lg_Whh + (size_t)t * D,
                 p.lg_Whh + (size_t)(t + 1) * D, sh_l, lane, o0, o1);
          o0 = wred(o0) + p.lg_bhh[t];
          o1 = wred(o1) + p.lg_bhh[t + 1];
          if (lane == 0) { ghl[t] = o0; ghl[t + 1] = o1; }
        }
      }
    } else {
      for (int t = gw * 2; t < 3 * D; t += nw * 2) {
        float o0, o1;
        dot8x2(p.lg_Whh + (size_t)t * D,
               p.lg_Whh + (size_t)(t + 1) * D, sh_l, lane, o0, o1);
        o0 = wred(o0) + p.lg_bhh[t];
        o1 = wred(o1) + p.lg_bhh[t + 1];
        if (lane == 0) { ghl[t] = o0; ghl[t + 1] = o1; }
      }
    }
    grid.sync();  // S1

    if (upd) {
      // ---- P2: h-combine (block-local, identical across blocks) ----
      if (step == 0) {
        for (int i = threadIdx.x; i < H; i += blockDim.x) {
          float r = sigmoidf_(qc[i] + p.hg_bih[i] + p.hg_bhh[i]);
          float z = sigmoidf_(qc[H + i] + p.hg_bih[H + i] + p.hg_bhh[H + i]);
          float n = tanhf(qc[2 * H + i] + p.hg_bih[2 * H + i] + r * p.hg_bhh[2 * H + i]);
          sh_h[i] = (1.f - z) * n;
        }
      } else {
        for (int i = threadIdx.x; i < H; i += blockDim.x) {
          float r = sigmoidf_(qc[i] + gi_l[i] + p.hg_bih[i] + ghh[i]);
          float z = sigmoidf_(qc[H + i] + gi_l[H + i] + p.hg_bih[H + i] + ghh[H + i]);
          float n = tanhf(qc[2 * H + i] + gi_l[2 * H + i] + p.hg_bih[2 * H + i]
                          + r * ghh[2 * H + i]);
          sh_h[i] = (1.f - z) * n + z * sh_h[i];
        }
      }
      __syncthreads();

      // ---- P3: directive + h-derived scalars ----
      for (int t = gw; t < D + 3; t += nw) {
        if (t < D) {
          float s = wred(dot16(p.hd_W + (size_t)t * H, sh_h, lane)) + p.hd_b[t];
          if (lane == 0) dirv[t] = tanhf(s);
        } else if (t == D) {
          float s = wred(dot16(p.hc_W, sh_h, lane)) + p.hc_b[0];
          if (lane == 0) scal[0] = sigmoidf_(s);
        } else if (t == D + 1) {
          float s = wred(dot16(p.halt_W, sh_h, lane));
          if (lane == 0) scal[1] = s;
        } else {
          float s = wred(dot16(p.reset_W, sh_h, lane));
          if (lane == 0) scal[2] = s;
        }
      }
      grid.sync();  // S2

      for (int j = threadIdx.x; j < D; j += blockDim.x) sh_dir[j] = dirv[j];
      __syncthreads();

      // ---- P4: gil = lg_Wih @ dirv + bih ----
      for (int t = gw * 2; t < 3 * D; t += nw * 2) {
        float o0, o1;
        dot8x2(p.lg_Wih + (size_t)t * D,
               p.lg_Wih + (size_t)(t + 1) * D, sh_dir, lane, o0, o1);
        o0 = wred(o0) + p.lg_bih[t];
        o1 = wred(o1) + p.lg_bih[t + 1];
        if (lane == 0) { gil[t] = o0; gil[t + 1] = o1; }
      }
      grid.sync();  // S3
    }

    // ---- P5: l-combine (block-local) ----
    if (step == 0) {
      for (int j = threadIdx.x; j < D; j += blockDim.x) {
        float r = sigmoidf_(gil[j] + p.lg_bhh[j]);
        float z = sigmoidf_(gil[D + j] + p.lg_bhh[D + j]);
        float n = tanhf(gil[2 * D + j] + r * p.lg_bhh[2 * D + j]);
        sh_l[j] = (1.f - z) * n;
      }
    } else {
      for (int j = threadIdx.x; j < D; j += blockDim.x) {
        float r = sigmoidf_(gil[j] + ghl[j]);
        float z = sigmoidf_(gil[D + j] + ghl[D + j]);
        float n = tanhf(gil[2 * D + j] + r * ghl[2 * D + j]);
        sh_l[j] = (1.f - z) * n + z * sh_l[j];
      }
    }
    __syncthreads();

    // ---- P6: res + l-derived scalars ----
    for (int pt = gw; pt < D / 2 + 2; pt += nw) {
      if (pt < D / 2) {
        int t = pt * 2;
        float o0, o1;
        dot8x2(p.lo_W + (size_t)t * D,
               p.lo_W + (size_t)(t + 1) * D, sh_l, lane, o0, o1);
        o0 = wred(o0) + p.lo_b[t];
        o1 = wred(o1) + p.lo_b[t + 1];
        if (lane == 0) { resv[t] = tanhf(o0); resv[t + 1] = tanhf(o1); }
      } else if (pt == D / 2) {
        float s = wred(dot8(p.halt_W + H, sh_l, lane));
        if (lane == 0) scal[8 + par * 2 + 0] = s;
      } else {
        float s = wred(dot8(p.reset_W + H, sh_l, lane));
        if (lane == 0) scal[8 + par * 2 + 1] = s;
      }
    }
    grid.sync();  // S4 (S2 on non-update steps)

    // ---- P7: uniform scalar resolution (eager; no speculation) ----
    mom = MOMC * mom + (1.f - MOMC) * scal[0];
    float halt = sigmoidf_(scal[1] + scal[8 + par * 2 + 0] + p.halt_b[0]);
    float pp = fminf(halt, 1.f - cum);
    cum += pp; rw += pp;
    if (tid < D) sum_reg += pp * resv[tid];
    if (cum > 0.95f) break;

    float reset_p = sigmoidf_(scal[2] + scal[8 + par * 2 + 1] +
                              p.reset_W[H + D] * mom + p.reset_b[0]);
    if ((reset_p > 0.7f) && (step > KSTEP)) {  // uniform branch, all blocks
      for (int t = gw; t < D; t += nw) {
        float s = wred(dot16(p.li_W + (size_t)t * H, sh_h, lane)) + p.li_b[t];
        if (lane == 0) lrs[t] = tanhf(s);
      }
      grid.sync();
      for (int j = threadIdx.x; j < D; j += blockDim.x) sh_l[j] = lrs[j];
      __syncthreads();
    }
    // no trailing sync: next step's writes go to parity-opposite buffers, and
    // every cross-block read/write pair is separated by >=1 grid.sync.
  }

  if (tid < D) p.out[tid] = sum_reg / fmaxf(rw, 1e-8f);
}

extern "C" void kernel_launch(void* const* d_in, const int* in_sizes, int n_in,
                              void* d_out, int out_size, void* d_ws, size_t ws_size,
                              hipStream_t stream) {
  Params prm;
  prm.query   = (const float*)d_in[0];
  prm.hg_Wih  = (const float*)d_in[1];
  prm.hg_Whh  = (const float*)d_in[2];
  prm.hg_bih  = (const float*)d_in[3];
  prm.hg_bhh  = (const float*)d_in[4];
  prm.hd_W    = (const float*)d_in[5];
  prm.hd_b    = (const float*)d_in[6];
  prm.hc_W    = (const float*)d_in[7];
  prm.hc_b    = (const float*)d_in[8];
  prm.lg_Wih  = (const float*)d_in[9];
  prm.lg_Whh  = (const float*)d_in[10];
  prm.lg_bih  = (const float*)d_in[11];
  prm.lg_bhh  = (const float*)d_in[12];
  prm.lo_W    = (const float*)d_in[13];
  prm.lo_b    = (const float*)d_in[14];
  prm.halt_W  = (const float*)d_in[15];
  prm.halt_b  = (const float*)d_in[16];
  prm.reset_W = (const float*)d_in[17];
  prm.reset_b = (const float*)d_in[18];
  prm.li_W    = (const float*)d_in[19];
  prm.li_b    = (const float*)d_in[20];
  prm.ws  = (float*)d_ws;
  prm.out = (float*)d_out;

  void* args[] = { &prm };
  const int grids[3] = { GRID, GRID / 2, GRID / 4 };
  for (int g = 0; g < 3; ++g) {
    hipError_t e = hipLaunchCooperativeKernel((const void*)reasoning_kernel,
                                              dim3(grids[g]), dim3(BLOCK),
                                              args, 0, stream);
    if (e == hipSuccess) break;
  }
}